// Round 13
// baseline (454.616 us; speedup 1.0000x reference)
//
#include <hip/hip_runtime.h>
#include <stdint.h>

#define T_STEPS 100
#define BATCH   256
#define NIN     784
#define NHID    512
#define NOUT    10

// ===========================================================================
// NUMERICS CONTRACT (validated PASS R5-R20):
//   * gemm1: per C element, fp32 single-accumulator fmaf chain, k ascending,
//     OpenBLAS kc=384 panel folds: cur1 = ((P1 + P2) + P3) + bias, each +
//     a single __fadd_rn (P1/P2 panels, tail acc3 + bias in leaky). BIT-EXACT.
//   * gemm2: f64 accumulation of fp32 products, +b2 in f64, single f32
//     rounding. R21 NOTE: f64 sum order = 8-elem h-ascending lane chains ->
//     6-step xor-butterfly tree over 64 lanes — deterministic; ~1ulp-f64
//     reassociation vs R20 (which itself passed with absmax 0.0625).
//   * recurrences: fp32 _rn ops, ((0.95*mem + cur) - rst), no contraction;
//     spike/reset = (mem > 1.0f). VERBATIM in all kernels.
// PERF JOURNAL:
//   * R8 582us. R9/R13/R17 REGRESSIONS -> REGISTER-CLIFF LAW: gemm1 must
//     keep acc[8][8], BK=8, 1 float4/matrix staging, untouched epilogue
//     (unique AGPR-clean point, VGPR 56). gemm1 ~259us = structure floor
//     (LDS-pipe bound 1.5x: 192cy LDS vs 128cy FMA per CU per kk).
//   * R12 542.8: dual-panel z=2, P2 in d_ws. R14 495: leaky v2.
//   * R15 483: ring16. R16 469: leaky v4 prod/cons. R18 452.6: gemm2 pad.
//   * R19 444.2: leaky v5 full-batch-row (2KB segments).
//   * R20 437.0: gemm2+lout fused (-7). Fused kernel self-audit found:
//     ps[8][64][10] f64 = 80B lane stride -> 8-way ds_write_b64 conflicts;
//     s_waitcnt(0) x2 per t-iter drains vmcnt -> serial HBM latency per t.
//   * R21: g2lout v2 — in-register 6-step __shfl_xor f64 butterfly replaces
//     the LDS reduction (no ps/ps2, no drains, loads pipeline). LDS 47->4KB.
//     Predict g2lout ~10us. Post-hoc: leaky = total - 259 - 10 - gaps;
//     if total ~430 stays, leaky ~150 and becomes R22's sole target.
// ===========================================================================

// ---------------------------------------------------------------------------
// GEMM1 dual-panel kernel: z=0 -> k 0..383 into C1; z=1 -> k 384..767 into
// C2. BM=BN=128, BK=8, 256 threads = 4 waves in 2x2; each wave 8x8 lanes;
// micro 8x8. Double-buffered LDS, one barrier per iteration, prefetch-ahead.
// Pure overwrite, epilogue untouched (keeps acc in AGPRs, VGPR ~56).
// DO NOT MODIFY (register-cliff law, R9/R13/R17).
// ---------------------------------------------------------------------------
#define BM 128
#define BN 128
#define BK 8
#define PANEL_K 384

__global__ __launch_bounds__(256) void gemm1_dual(
    const float* __restrict__ X, const float* __restrict__ W,
    float* __restrict__ C1, float* __restrict__ C2)
{
    __shared__ float As[2][BK][BM + 4];   // 2 x 4224 B
    __shared__ float Bs[2][BK][BN + 4];   // 2 x 4224 B

    const int tid = threadIdx.x;
    const int bm  = blockIdx.x * BM;
    const int bn  = blockIdx.y * BN;
    const int kb  = blockIdx.z ? PANEL_K : 0;
    float* __restrict__ C = blockIdx.z ? C2 : C1;

    // staging: 128 rows x 8 k = 256 float4
    const int row  = tid >> 1;           // 0..127
    const int koff = (tid & 1) * 4;      // 0 or 4

    // compute mapping: wave 2x2, lane 8x8, micro 8x8
    const int w    = tid >> 6;
    const int lane = tid & 63;
    const int tm   = (w & 1) * 64 + (lane & 7) * 8;    // 0..120
    const int tn   = (w >> 1) * 64 + (lane >> 3) * 8;  // 0..120

    float acc[8][8];
    #pragma unroll
    for (int i = 0; i < 8; ++i)
        #pragma unroll
        for (int j = 0; j < 8; ++j) acc[i][j] = 0.f;

    const float* Xp = X + (size_t)(bm + row) * NIN + kb + koff;
    const float* Wp = W + (size_t)(bn + row) * NIN + kb + koff;

    // prologue: stage iter 0 into buffer 0
    float4 pa = *(const float4*)(Xp);
    float4 pb = *(const float4*)(Wp);
    As[0][koff+0][row] = pa.x; As[0][koff+1][row] = pa.y;
    As[0][koff+2][row] = pa.z; As[0][koff+3][row] = pa.w;
    Bs[0][koff+0][row] = pb.x; Bs[0][koff+1][row] = pb.y;
    Bs[0][koff+2][row] = pb.z; Bs[0][koff+3][row] = pb.w;

    const int NITER = PANEL_K / BK;   // 48
    for (int it = 0; it < NITER; ++it) {
        const int cur = it & 1;
        __syncthreads();

        if (it + 1 < NITER) {
            const int k0 = (it + 1) * BK;
            pa = *(const float4*)(Xp + k0);
            pb = *(const float4*)(Wp + k0);
        }

        #pragma unroll
        for (int kk = 0; kk < BK; ++kk) {   // k ascending
            float4 av0 = *(const float4*)&As[cur][kk][tm];
            float4 av1 = *(const float4*)&As[cur][kk][tm + 4];
            float4 bv0 = *(const float4*)&Bs[cur][kk][tn];
            float4 bv1 = *(const float4*)&Bs[cur][kk][tn + 4];
            float a[8] = {av0.x, av0.y, av0.z, av0.w, av1.x, av1.y, av1.z, av1.w};
            float b[8] = {bv0.x, bv0.y, bv0.z, bv0.w, bv1.x, bv1.y, bv1.z, bv1.w};
            #pragma unroll
            for (int i = 0; i < 8; ++i)
                #pragma unroll
                for (int j = 0; j < 8; ++j)
                    acc[i][j] = fmaf(a[i], b[j], acc[i][j]);
        }

        if (it + 1 < NITER) {
            const int nxt = cur ^ 1;
            As[nxt][koff+0][row] = pa.x; As[nxt][koff+1][row] = pa.y;
            As[nxt][koff+2][row] = pa.z; As[nxt][koff+3][row] = pa.w;
            Bs[nxt][koff+0][row] = pb.x; Bs[nxt][koff+1][row] = pb.y;
            Bs[nxt][koff+2][row] = pb.z; Bs[nxt][koff+3][row] = pb.w;
        }
    }

    #pragma unroll
    for (int i = 0; i < 8; ++i) {
        size_t r = (size_t)(bm + tm + i) * NHID + bn + tn;
        *(float4*)&C[r]     = make_float4(acc[i][0], acc[i][1], acc[i][2], acc[i][3]);
        *(float4*)&C[r + 4] = make_float4(acc[i][4], acc[i][5], acc[i][6], acc[i][7]);
    }
}

// ---------------------------------------------------------------------------
// Hidden Leaky recurrence, fused with the GEMM1 tail fold (v5):
// producer/consumer wave specialization, FULL-BATCH-ROW blocks.
// 256 blocks x 1024 threads; block bb owns all h for batch row bb.
// tid<512: consumers (bit-exact chain math); tid>=512: producers stream
// P1/P2 into LDS dbuf FIFO in chunks of 8 t. See R16/R19 notes.
// ---------------------------------------------------------------------------
__global__ __launch_bounds__(1024) void leaky_hidden_fused(
    float* __restrict__ mem_io,        // P1 on entry, mem1 on exit
    const float* c2,                   // P2 partial (d_ws; may alias spk_out)
    float* spk_out,
    const float* __restrict__ X,
    const float* __restrict__ W1,
    const float* __restrict__ b1)
{
    __shared__ float4 xs4[T_STEPS][4];     // X[bb][t][768..783], 6.4 KB
    __shared__ float  p1s[2][8][NHID];     // 32 KB
    __shared__ float  p2s[2][8][NHID];     // 32 KB

    const int tid = threadIdx.x;
    const int bb  = blockIdx.x;                    // batch row 0..255
    const size_t STRIDE = (size_t)BATCH * NHID;
    const size_t base   = (size_t)bb * NHID;

    // stage X tail: 400 float4 (threads 0..399, one each)
    if (tid < T_STEPS * 4) {
        const int t = tid >> 2, q = tid & 3;
        xs4[t][q] = *(const float4*)(X + (size_t)t * BATCH * NIN
                                       + (size_t)bb * NIN + 768 + q * 4);
    }

    const bool producer = (tid >= 512);
    const int  lane     = tid & 511;               // col offset 0..511
    const size_t col    = base + lane;

    float wt[16];
    float bias = 0.f;
    float mem  = 0.f;

    if (producer) {
        // prologue: chunk 0 (t = 0..7) into buf 0
        float v1[8], v2[8];
        #pragma unroll
        for (int j = 0; j < 8; ++j) {
            v1[j] = mem_io[col + (size_t)j * STRIDE];
            v2[j] = c2[col + (size_t)j * STRIDE];
        }
        #pragma unroll
        for (int j = 0; j < 8; ++j) {
            p1s[0][j][lane] = v1[j];
            p2s[0][j][lane] = v2[j];
        }
    } else {
        const int h = lane;                        // 0..511
        const float* wp = W1 + (size_t)h * NIN + 768;
        float4 w0  = *(const float4*)(wp);
        float4 w1v = *(const float4*)(wp + 4);
        float4 w2v = *(const float4*)(wp + 8);
        float4 w3v = *(const float4*)(wp + 12);
        wt[0]=w0.x;  wt[1]=w0.y;  wt[2]=w0.z;  wt[3]=w0.w;
        wt[4]=w1v.x; wt[5]=w1v.y; wt[6]=w1v.z; wt[7]=w1v.w;
        wt[8]=w2v.x; wt[9]=w2v.y; wt[10]=w2v.z; wt[11]=w2v.w;
        wt[12]=w3v.x; wt[13]=w3v.y; wt[14]=w3v.z; wt[15]=w3v.w;
        bias = b1[h];
    }

    __syncthreads();   // xs4 + chunk 0 ready

    // chunks: c = 0..12; chunk c covers t = 8c .. 8c+nt-1 (nt=4 for c=12)
    for (int c = 0; c <= 12; ++c) {
        if (producer) {
            if (c < 12) {
                const int t0 = (c + 1) * 8;
                const int nb = (c + 1 == 12) ? 4 : 8;
                float v1[8], v2[8];
                #pragma unroll
                for (int j = 0; j < 8; ++j) {
                    if (j < nb) {
                        v1[j] = mem_io[col + (size_t)(t0 + j) * STRIDE];
                        v2[j] = c2[col + (size_t)(t0 + j) * STRIDE];
                    }
                }
                const int pb = (c + 1) & 1;
                #pragma unroll
                for (int j = 0; j < 8; ++j) {
                    if (j < nb) {
                        p1s[pb][j][lane] = v1[j];
                        p2s[pb][j][lane] = v2[j];
                    }
                }
            }
        } else {
            const int nt = (c == 12) ? 4 : 8;
            const int cb = c & 1;
            #pragma unroll
            for (int j = 0; j < 8; ++j) {
                if (j < nt) {
                    const int t = c * 8 + j;
                    const float p1 = p1s[cb][j][lane];
                    const float p2 = p2s[cb][j][lane];
                    float4 v0 = xs4[t][0], v1 = xs4[t][1];
                    float4 v2 = xs4[t][2], v3 = xs4[t][3];
                    // acc3: 16-k ascending single-accumulator fmaf chain
                    float a = 0.f;
                    a = fmaf(v0.x, wt[0], a);  a = fmaf(v0.y, wt[1], a);
                    a = fmaf(v0.z, wt[2], a);  a = fmaf(v0.w, wt[3], a);
                    a = fmaf(v1.x, wt[4], a);  a = fmaf(v1.y, wt[5], a);
                    a = fmaf(v1.z, wt[6], a);  a = fmaf(v1.w, wt[7], a);
                    a = fmaf(v2.x, wt[8], a);  a = fmaf(v2.y, wt[9], a);
                    a = fmaf(v2.z, wt[10], a); a = fmaf(v2.w, wt[11], a);
                    a = fmaf(v3.x, wt[12], a); a = fmaf(v3.y, wt[13], a);
                    a = fmaf(v3.z, wt[14], a); a = fmaf(v3.w, wt[15], a);

                    const float cur = __fadd_rn(__fadd_rn(__fadd_rn(p1, p2), a), bias);
                    const float rst = (mem > 1.0f) ? 1.0f : 0.0f;
                    mem = __fsub_rn(__fadd_rn(__fmul_rn(0.95f, mem), cur), rst);

                    const size_t off = col + (size_t)t * STRIDE;
                    spk_out[off] = (mem > 1.0f) ? 1.0f : 0.0f;
                    mem_io[off]  = mem;
                }
            }
        }
        __syncthreads();
    }
}

// ---------------------------------------------------------------------------
// GEMM2 + output Leaky, fused (v2, R21). One block per batch row b, 512
// threads = 8 waves. W2 in registers (lane l holds W2[o][8l..8l+7] ∀o).
// Wave w handles t = w, w+8, ...: 2 coalesced float4 spk1 loads, per-o
// 8-element h-ascending f64 fma chain, then a 6-step __shfl_xor f64
// butterfly (deterministic tree) — NO LDS reduction, NO waitcnt drains,
// loads pipeline across t-iterations. Lanes 0..9 write cur2 + LDS cache.
// One barrier; threads 0..9 run the VERBATIM leaky_out recurrence.
// ---------------------------------------------------------------------------
__global__ __launch_bounds__(512) void gemm2_lout_fused(
    const float* __restrict__ spk1, const float* __restrict__ W2,
    const float* __restrict__ b2, float* __restrict__ cur2,
    float* __restrict__ spk2, float* __restrict__ mem2)
{
    __shared__ float c2s[T_STEPS][NOUT];   // 4 KB: cur2 cache for recurrence

    const int tid  = threadIdx.x;
    const int w    = tid >> 6;          // wave 0..7
    const int lane = tid & 63;          // 0..63
    const int b    = blockIdx.x;        // batch row

    // W2[o][8l..8l+7] for all o -> 80 regs
    float w2r[10][8];
    #pragma unroll
    for (int o = 0; o < NOUT; ++o) {
        float4 a0 = *(const float4*)(W2 + (size_t)o * NHID + 8 * lane);
        float4 a1 = *(const float4*)(W2 + (size_t)o * NHID + 8 * lane + 4);
        w2r[o][0]=a0.x; w2r[o][1]=a0.y; w2r[o][2]=a0.z; w2r[o][3]=a0.w;
        w2r[o][4]=a1.x; w2r[o][5]=a1.y; w2r[o][6]=a1.z; w2r[o][7]=a1.w;
    }
    const float b2l = (lane < NOUT) ? b2[lane] : 0.f;

    for (int t = w; t < T_STEPS; t += 8) {
        // spk1 row slice: 8 floats at h = 8*lane
        const float* sp = spk1 + (size_t)t * (BATCH * NHID)
                               + (size_t)b * NHID + 8 * lane;
        float4 s0 = *(const float4*)(sp);
        float4 s1 = *(const float4*)(sp + 4);
        const float s[8] = {s0.x, s0.y, s0.z, s0.w, s1.x, s1.y, s1.z, s1.w};

        // per-o 8-element h-ascending f64 chains, then butterfly reduce
        double d[10];
        #pragma unroll
        for (int o = 0; o < NOUT; ++o) {
            double a = 0.0;
            #pragma unroll
            for (int j = 0; j < 8; ++j)
                a = fma((double)s[j], (double)w2r[o][j], a);
            // 6-step xor butterfly over 64 lanes (deterministic tree)
            a += __shfl_xor(a, 32, 64);
            a += __shfl_xor(a, 16, 64);
            a += __shfl_xor(a,  8, 64);
            a += __shfl_xor(a,  4, 64);
            a += __shfl_xor(a,  2, 64);
            a += __shfl_xor(a,  1, 64);
            d[o] = a;
        }

        if (lane < NOUT) {
            // static select of d[lane] (no runtime register indexing)
            double dv = d[0];
            if (lane == 1) dv = d[1];
            if (lane == 2) dv = d[2];
            if (lane == 3) dv = d[3];
            if (lane == 4) dv = d[4];
            if (lane == 5) dv = d[5];
            if (lane == 6) dv = d[6];
            if (lane == 7) dv = d[7];
            if (lane == 8) dv = d[8];
            if (lane == 9) dv = d[9];
            const float c = (float)(dv + (double)b2l);
            cur2[(size_t)t * (BATCH * NOUT) + (size_t)b * NOUT + lane] = c;
            c2s[t][lane] = c;
        }
    }

    __syncthreads();   // all cur2 cached

    // output Leaky recurrence: VERBATIM fp32 _rn chain, threads 0..9
    if (tid < NOUT) {
        const int o = tid;
        float mem = 0.f;
        for (int t = 0; t < T_STEPS; ++t) {
            const float cur = c2s[t][o];
            const float rst = (mem > 1.0f) ? 1.0f : 0.0f;
            mem = __fsub_rn(__fadd_rn(__fmul_rn(0.95f, mem), cur), rst);
            const size_t off = (size_t)t * (BATCH * NOUT) + (size_t)b * NOUT + o;
            spk2[off] = (mem > 1.0f) ? 1.0f : 0.0f;
            mem2[off] = mem;
        }
    }
}

// ---------------------------------------------------------------------------
extern "C" void kernel_launch(void* const* d_in, const int* in_sizes, int n_in,
                              void* d_out, int out_size, void* d_ws, size_t ws_size,
                              hipStream_t stream) {
    const float* x  = (const float*)d_in[0];   // (100, 256, 784)
    const float* w1 = (const float*)d_in[1];   // (512, 784)
    const float* b1 = (const float*)d_in[2];   // (512,)
    const float* w2 = (const float*)d_in[3];   // (10, 512)
    const float* b2 = (const float*)d_in[4];   // (10,)

    float* out = (float*)d_out;
    // Output tuple order: (cur2, spk2, spk1, mem2, mem1), each stacked over T.
    float* cur2_out = out;                       // 256000
    float* spk2_out = out + 256000;              // 256000
    float* spk1_out = out + 512000;              // 13107200
    float* mem2_out = out + 13619200;            // 256000
    float* mem1_out = out + 13875200;            // 13107200

    const int M = T_STEPS * BATCH;               // 25600

    // P2 scratch: prefer d_ws (no aliasing); fall back to spk1 region
    // (chunk-disjoint, barrier-ordered aliasing) only if ws too small.
    const size_t p2_bytes = (size_t)M * NHID * sizeof(float);   // 52.4 MB
    float* p2buf = (d_ws != nullptr && ws_size >= p2_bytes)
                       ? (float*)d_ws : spk1_out;

    // 1) P1 -> mem1 region, P2 -> p2buf, one z=2 launch.
    dim3 gp(M / BM, NHID / BN, 2);               // (200, 4, 2) = 1600 blocks
    gemm1_dual<<<gp, 256, 0, stream>>>(x, w1, mem1_out, p2buf);

    // 2) hidden Leaky chains + P3 tail fold + bias (fp32 _rn),
    //    full-batch-row producer/consumer blocks: 256 blocks x 1024 threads.
    leaky_hidden_fused<<<BATCH, 1024, 0, stream>>>(
        mem1_out, p2buf, spk1_out, x, w1, b1);

    // 3) cur2 = spk1 @ W2^T + b2 (f64 acc -> f32) + output Leaky, fused:
    //    one block per batch row.
    gemm2_lout_fused<<<BATCH, 512, 0, stream>>>(
        spk1_out, w2, b2, cur2_out, spk2_out, mem2_out);
}

// Round 14
// 445.249 us; speedup vs baseline: 1.0210x; 1.0210x over previous
//
#include <hip/hip_runtime.h>
#include <stdint.h>

#define T_STEPS 100
#define BATCH   256
#define NIN     784
#define NHID    512
#define NOUT    10

// ===========================================================================
// NUMERICS CONTRACT (validated PASS R5-R20):
//   * gemm1: per C element, fp32 single-accumulator fmaf chain, k ascending,
//     OpenBLAS kc=384 panel folds: cur1 = ((P1 + P2) + P3) + bias, each +
//     a single __fadd_rn (P1/P2 panels, tail acc3 + bias in leaky). BIT-EXACT.
//   * gemm2: f64 accumulation of fp32 products, +b2 in f64, single f32
//     rounding. Sum order (R20, validated absmax 0.0625): 8-elem h-ascending
//     lane chains -> 16-partial l-ascending group sums -> 4 g-ascending
//     adds. R22 keeps this order exactly.
//   * recurrences: fp32 _rn ops, ((0.95*mem + cur) - rst), no contraction;
//     spike/reset = (mem > 1.0f). VERBATIM in all kernels.
// PERF JOURNAL:
//   * R8 582us. R9/R13/R17 REGRESSIONS -> REGISTER-CLIFF LAW: gemm1 must
//     keep acc[8][8], BK=8, 1 float4/matrix staging, untouched epilogue
//     (unique AGPR-clean point, VGPR 56). gemm1 ~259us = structure floor
//     (CU-level LDS-pipe bound ~3x: 8 waves x 48cy LDS vs 128cy FMA/kk).
//   * R12 542.8: dual-panel z=2, P2 in d_ws. R14 495: leaky v2.
//   * R15 483: ring16. R16 469: leaky v4 prod/cons. R18 452.6: gemm2 pad.
//   * R19 444.2: leaky v5 full-batch-row (2KB segments).
//   * R20 437.0 BEST: gemm2+lout fused. Defects found: ps[8][64][10] f64 =
//     80B lane stride -> 8-way ds_write_b64 conflict; s_waitcnt(0) x2/t-iter
//     drains vmcnt -> loads never pipeline across t.
//   * R21 454.6 REGRESSION: f64 shfl butterfly = 2 ds_bpermute per shuffle
//     x 60/t-iter = 120 LDS ops vs R20's ~20. LESSON: butterfly loses when
//     outputs (10) << lanes (64); LDS reduction has 6x fewer pipe ops.
//   * R22: g2lout v3 = R20 structure + ps pad [8][64][11] (22-dword lane
//     stride, gcd(22,32)=2 -> 2-way free) + lgkm-only waitcnt (vmcnt keeps
//     pipelining). Same f64 sum order as validated R20.
// ===========================================================================

// ---------------------------------------------------------------------------
// GEMM1 dual-panel kernel: z=0 -> k 0..383 into C1; z=1 -> k 384..767 into
// C2. BM=BN=128, BK=8, 256 threads = 4 waves in 2x2; each wave 8x8 lanes;
// micro 8x8. Double-buffered LDS, one barrier per iteration, prefetch-ahead.
// Pure overwrite, epilogue untouched (keeps acc in AGPRs, VGPR ~56).
// DO NOT MODIFY (register-cliff law, R9/R13/R17).
// ---------------------------------------------------------------------------
#define BM 128
#define BN 128
#define BK 8
#define PANEL_K 384

__global__ __launch_bounds__(256) void gemm1_dual(
    const float* __restrict__ X, const float* __restrict__ W,
    float* __restrict__ C1, float* __restrict__ C2)
{
    __shared__ float As[2][BK][BM + 4];   // 2 x 4224 B
    __shared__ float Bs[2][BK][BN + 4];   // 2 x 4224 B

    const int tid = threadIdx.x;
    const int bm  = blockIdx.x * BM;
    const int bn  = blockIdx.y * BN;
    const int kb  = blockIdx.z ? PANEL_K : 0;
    float* __restrict__ C = blockIdx.z ? C2 : C1;

    // staging: 128 rows x 8 k = 256 float4
    const int row  = tid >> 1;           // 0..127
    const int koff = (tid & 1) * 4;      // 0 or 4

    // compute mapping: wave 2x2, lane 8x8, micro 8x8
    const int w    = tid >> 6;
    const int lane = tid & 63;
    const int tm   = (w & 1) * 64 + (lane & 7) * 8;    // 0..120
    const int tn   = (w >> 1) * 64 + (lane >> 3) * 8;  // 0..120

    float acc[8][8];
    #pragma unroll
    for (int i = 0; i < 8; ++i)
        #pragma unroll
        for (int j = 0; j < 8; ++j) acc[i][j] = 0.f;

    const float* Xp = X + (size_t)(bm + row) * NIN + kb + koff;
    const float* Wp = W + (size_t)(bn + row) * NIN + kb + koff;

    // prologue: stage iter 0 into buffer 0
    float4 pa = *(const float4*)(Xp);
    float4 pb = *(const float4*)(Wp);
    As[0][koff+0][row] = pa.x; As[0][koff+1][row] = pa.y;
    As[0][koff+2][row] = pa.z; As[0][koff+3][row] = pa.w;
    Bs[0][koff+0][row] = pb.x; Bs[0][koff+1][row] = pb.y;
    Bs[0][koff+2][row] = pb.z; Bs[0][koff+3][row] = pb.w;

    const int NITER = PANEL_K / BK;   // 48
    for (int it = 0; it < NITER; ++it) {
        const int cur = it & 1;
        __syncthreads();

        if (it + 1 < NITER) {
            const int k0 = (it + 1) * BK;
            pa = *(const float4*)(Xp + k0);
            pb = *(const float4*)(Wp + k0);
        }

        #pragma unroll
        for (int kk = 0; kk < BK; ++kk) {   // k ascending
            float4 av0 = *(const float4*)&As[cur][kk][tm];
            float4 av1 = *(const float4*)&As[cur][kk][tm + 4];
            float4 bv0 = *(const float4*)&Bs[cur][kk][tn];
            float4 bv1 = *(const float4*)&Bs[cur][kk][tn + 4];
            float a[8] = {av0.x, av0.y, av0.z, av0.w, av1.x, av1.y, av1.z, av1.w};
            float b[8] = {bv0.x, bv0.y, bv0.z, bv0.w, bv1.x, bv1.y, bv1.z, bv1.w};
            #pragma unroll
            for (int i = 0; i < 8; ++i)
                #pragma unroll
                for (int j = 0; j < 8; ++j)
                    acc[i][j] = fmaf(a[i], b[j], acc[i][j]);
        }

        if (it + 1 < NITER) {
            const int nxt = cur ^ 1;
            As[nxt][koff+0][row] = pa.x; As[nxt][koff+1][row] = pa.y;
            As[nxt][koff+2][row] = pa.z; As[nxt][koff+3][row] = pa.w;
            Bs[nxt][koff+0][row] = pb.x; Bs[nxt][koff+1][row] = pb.y;
            Bs[nxt][koff+2][row] = pb.z; Bs[nxt][koff+3][row] = pb.w;
        }
    }

    #pragma unroll
    for (int i = 0; i < 8; ++i) {
        size_t r = (size_t)(bm + tm + i) * NHID + bn + tn;
        *(float4*)&C[r]     = make_float4(acc[i][0], acc[i][1], acc[i][2], acc[i][3]);
        *(float4*)&C[r + 4] = make_float4(acc[i][4], acc[i][5], acc[i][6], acc[i][7]);
    }
}

// ---------------------------------------------------------------------------
// Hidden Leaky recurrence, fused with the GEMM1 tail fold (v5):
// producer/consumer wave specialization, FULL-BATCH-ROW blocks.
// 256 blocks x 1024 threads; block bb owns all h for batch row bb.
// tid<512: consumers (bit-exact chain math); tid>=512: producers stream
// P1/P2 into LDS dbuf FIFO in chunks of 8 t. See R16/R19 notes.
// ---------------------------------------------------------------------------
__global__ __launch_bounds__(1024) void leaky_hidden_fused(
    float* __restrict__ mem_io,        // P1 on entry, mem1 on exit
    const float* c2,                   // P2 partial (d_ws; may alias spk_out)
    float* spk_out,
    const float* __restrict__ X,
    const float* __restrict__ W1,
    const float* __restrict__ b1)
{
    __shared__ float4 xs4[T_STEPS][4];     // X[bb][t][768..783], 6.4 KB
    __shared__ float  p1s[2][8][NHID];     // 32 KB
    __shared__ float  p2s[2][8][NHID];     // 32 KB

    const int tid = threadIdx.x;
    const int bb  = blockIdx.x;                    // batch row 0..255
    const size_t STRIDE = (size_t)BATCH * NHID;
    const size_t base   = (size_t)bb * NHID;

    // stage X tail: 400 float4 (threads 0..399, one each)
    if (tid < T_STEPS * 4) {
        const int t = tid >> 2, q = tid & 3;
        xs4[t][q] = *(const float4*)(X + (size_t)t * BATCH * NIN
                                       + (size_t)bb * NIN + 768 + q * 4);
    }

    const bool producer = (tid >= 512);
    const int  lane     = tid & 511;               // col offset 0..511
    const size_t col    = base + lane;

    float wt[16];
    float bias = 0.f;
    float mem  = 0.f;

    if (producer) {
        // prologue: chunk 0 (t = 0..7) into buf 0
        float v1[8], v2[8];
        #pragma unroll
        for (int j = 0; j < 8; ++j) {
            v1[j] = mem_io[col + (size_t)j * STRIDE];
            v2[j] = c2[col + (size_t)j * STRIDE];
        }
        #pragma unroll
        for (int j = 0; j < 8; ++j) {
            p1s[0][j][lane] = v1[j];
            p2s[0][j][lane] = v2[j];
        }
    } else {
        const int h = lane;                        // 0..511
        const float* wp = W1 + (size_t)h * NIN + 768;
        float4 w0  = *(const float4*)(wp);
        float4 w1v = *(const float4*)(wp + 4);
        float4 w2v = *(const float4*)(wp + 8);
        float4 w3v = *(const float4*)(wp + 12);
        wt[0]=w0.x;  wt[1]=w0.y;  wt[2]=w0.z;  wt[3]=w0.w;
        wt[4]=w1v.x; wt[5]=w1v.y; wt[6]=w1v.z; wt[7]=w1v.w;
        wt[8]=w2v.x; wt[9]=w2v.y; wt[10]=w2v.z; wt[11]=w2v.w;
        wt[12]=w3v.x; wt[13]=w3v.y; wt[14]=w3v.z; wt[15]=w3v.w;
        bias = b1[h];
    }

    __syncthreads();   // xs4 + chunk 0 ready

    // chunks: c = 0..12; chunk c covers t = 8c .. 8c+nt-1 (nt=4 for c=12)
    for (int c = 0; c <= 12; ++c) {
        if (producer) {
            if (c < 12) {
                const int t0 = (c + 1) * 8;
                const int nb = (c + 1 == 12) ? 4 : 8;
                float v1[8], v2[8];
                #pragma unroll
                for (int j = 0; j < 8; ++j) {
                    if (j < nb) {
                        v1[j] = mem_io[col + (size_t)(t0 + j) * STRIDE];
                        v2[j] = c2[col + (size_t)(t0 + j) * STRIDE];
                    }
                }
                const int pb = (c + 1) & 1;
                #pragma unroll
                for (int j = 0; j < 8; ++j) {
                    if (j < nb) {
                        p1s[pb][j][lane] = v1[j];
                        p2s[pb][j][lane] = v2[j];
                    }
                }
            }
        } else {
            const int nt = (c == 12) ? 4 : 8;
            const int cb = c & 1;
            #pragma unroll
            for (int j = 0; j < 8; ++j) {
                if (j < nt) {
                    const int t = c * 8 + j;
                    const float p1 = p1s[cb][j][lane];
                    const float p2 = p2s[cb][j][lane];
                    float4 v0 = xs4[t][0], v1 = xs4[t][1];
                    float4 v2 = xs4[t][2], v3 = xs4[t][3];
                    // acc3: 16-k ascending single-accumulator fmaf chain
                    float a = 0.f;
                    a = fmaf(v0.x, wt[0], a);  a = fmaf(v0.y, wt[1], a);
                    a = fmaf(v0.z, wt[2], a);  a = fmaf(v0.w, wt[3], a);
                    a = fmaf(v1.x, wt[4], a);  a = fmaf(v1.y, wt[5], a);
                    a = fmaf(v1.z, wt[6], a);  a = fmaf(v1.w, wt[7], a);
                    a = fmaf(v2.x, wt[8], a);  a = fmaf(v2.y, wt[9], a);
                    a = fmaf(v2.z, wt[10], a); a = fmaf(v2.w, wt[11], a);
                    a = fmaf(v3.x, wt[12], a); a = fmaf(v3.y, wt[13], a);
                    a = fmaf(v3.z, wt[14], a); a = fmaf(v3.w, wt[15], a);

                    const float cur = __fadd_rn(__fadd_rn(__fadd_rn(p1, p2), a), bias);
                    const float rst = (mem > 1.0f) ? 1.0f : 0.0f;
                    mem = __fsub_rn(__fadd_rn(__fmul_rn(0.95f, mem), cur), rst);

                    const size_t off = col + (size_t)t * STRIDE;
                    spk_out[off] = (mem > 1.0f) ? 1.0f : 0.0f;
                    mem_io[off]  = mem;
                }
            }
        }
        __syncthreads();
    }
}

// ---------------------------------------------------------------------------
// GEMM2 + output Leaky, fused (v3, R22 = R20 structure + conflict/drain
// fixes). One block per batch row b, 512 threads = 8 waves. W2 in REGS.
// Wave w handles t = w, w+8, ...:
//   lanes: 2 coalesced float4 spk1 loads, per-o 8-element h-ascending f64
//   fma chain -> ps[w][lane][o]  (pad 11: 22-dword lane stride, 2-way free)
//   stage2a (40 lanes): 16-partial l-ascending f64 sums -> ps2
//   stage2b (10 lanes): 4 g-ascending adds + b2 (f64) -> single f32 round
// lgkm-only waitcnts between stages (vmcnt stays outstanding -> next t's
// loads pipeline). One barrier; threads 0..9 run VERBATIM recurrence.
// f64 sum order identical to validated R20.
// ---------------------------------------------------------------------------
__global__ __launch_bounds__(512) void gemm2_lout_fused(
    const float* __restrict__ spk1, const float* __restrict__ W2,
    const float* __restrict__ b2, float* __restrict__ cur2,
    float* __restrict__ spk2, float* __restrict__ mem2)
{
    __shared__ double ps [8][64][11];   // 44 KB, lane stride 88 B (2-way)
    __shared__ double ps2[8][4][11];    // 2.75 KB
    __shared__ float  c2s[T_STEPS][NOUT]; // 4 KB

    const int tid  = threadIdx.x;
    const int w    = tid >> 6;          // wave 0..7
    const int lane = tid & 63;          // 0..63
    const int b    = blockIdx.x;        // batch row

    // W2[o][8l..8l+7] for all o -> 80 regs
    float w2r[10][8];
    #pragma unroll
    for (int o = 0; o < NOUT; ++o) {
        float4 a0 = *(const float4*)(W2 + (size_t)o * NHID + 8 * lane);
        float4 a1 = *(const float4*)(W2 + (size_t)o * NHID + 8 * lane + 4);
        w2r[o][0]=a0.x; w2r[o][1]=a0.y; w2r[o][2]=a0.z; w2r[o][3]=a0.w;
        w2r[o][4]=a1.x; w2r[o][5]=a1.y; w2r[o][6]=a1.z; w2r[o][7]=a1.w;
    }

    for (int t = w; t < T_STEPS; t += 8) {
        // spk1 row slice: 8 floats at h = 8*lane
        const float* sp = spk1 + (size_t)t * (BATCH * NHID)
                               + (size_t)b * NHID + 8 * lane;
        float4 s0 = *(const float4*)(sp);
        float4 s1 = *(const float4*)(sp + 4);
        const float s[8] = {s0.x, s0.y, s0.z, s0.w, s1.x, s1.y, s1.z, s1.w};

        // per-o 8-element h-ascending f64 chains
        #pragma unroll
        for (int o = 0; o < NOUT; ++o) {
            double d = 0.0;
            #pragma unroll
            for (int j = 0; j < 8; ++j)
                d = fma((double)s[j], (double)w2r[o][j], d);
            ps[w][lane][o] = d;
        }
        asm volatile("s_waitcnt lgkmcnt(0)" ::: "memory");  // DS only

        // stage 2a: 40 lanes (o = lane>>2, g = lane&3): sum 16 partials,
        // l ascending within group
        if (lane < 40) {
            const int o = lane >> 2, g = lane & 3;
            double d = 0.0;
            #pragma unroll
            for (int l2 = 0; l2 < 16; ++l2)
                d += ps[w][g * 16 + l2][o];
            ps2[w][g][o] = d;
        }
        asm volatile("s_waitcnt lgkmcnt(0)" ::: "memory");  // DS only

        // stage 2b: 10 lanes: 4 g-ascending adds + b2 (f64), single rounding
        if (lane < 10) {
            const int o = lane;
            double d = ((ps2[w][0][o] + ps2[w][1][o]) + ps2[w][2][o])
                       + ps2[w][3][o];
            const float c = (float)(d + (double)b2[o]);
            cur2[(size_t)t * (BATCH * NOUT) + (size_t)b * NOUT + o] = c;
            c2s[t][o] = c;
        }
    }

    __syncthreads();   // all cur2 cached

    // output Leaky recurrence: VERBATIM fp32 _rn chain, threads 0..9
    if (tid < NOUT) {
        const int o = tid;
        float mem = 0.f;
        for (int t = 0; t < T_STEPS; ++t) {
            const float cur = c2s[t][o];
            const float rst = (mem > 1.0f) ? 1.0f : 0.0f;
            mem = __fsub_rn(__fadd_rn(__fmul_rn(0.95f, mem), cur), rst);
            const size_t off = (size_t)t * (BATCH * NOUT) + (size_t)b * NOUT + o;
            spk2[off] = (mem > 1.0f) ? 1.0f : 0.0f;
            mem2[off] = mem;
        }
    }
}

// ---------------------------------------------------------------------------
extern "C" void kernel_launch(void* const* d_in, const int* in_sizes, int n_in,
                              void* d_out, int out_size, void* d_ws, size_t ws_size,
                              hipStream_t stream) {
    const float* x  = (const float*)d_in[0];   // (100, 256, 784)
    const float* w1 = (const float*)d_in[1];   // (512, 784)
    const float* b1 = (const float*)d_in[2];   // (512,)
    const float* w2 = (const float*)d_in[3];   // (10, 512)
    const float* b2 = (const float*)d_in[4];   // (10,)

    float* out = (float*)d_out;
    // Output tuple order: (cur2, spk2, spk1, mem2, mem1), each stacked over T.
    float* cur2_out = out;                       // 256000
    float* spk2_out = out + 256000;              // 256000
    float* spk1_out = out + 512000;              // 13107200
    float* mem2_out = out + 13619200;            // 256000
    float* mem1_out = out + 13875200;            // 13107200

    const int M = T_STEPS * BATCH;               // 25600

    // P2 scratch: prefer d_ws (no aliasing); fall back to spk1 region
    // (chunk-disjoint, barrier-ordered aliasing) only if ws too small.
    const size_t p2_bytes = (size_t)M * NHID * sizeof(float);   // 52.4 MB
    float* p2buf = (d_ws != nullptr && ws_size >= p2_bytes)
                       ? (float*)d_ws : spk1_out;

    // 1) P1 -> mem1 region, P2 -> p2buf, one z=2 launch.
    dim3 gp(M / BM, NHID / BN, 2);               // (200, 4, 2) = 1600 blocks
    gemm1_dual<<<gp, 256, 0, stream>>>(x, w1, mem1_out, p2buf);

    // 2) hidden Leaky chains + P3 tail fold + bias (fp32 _rn),
    //    full-batch-row producer/consumer blocks: 256 blocks x 1024 threads.
    leaky_hidden_fused<<<BATCH, 1024, 0, stream>>>(
        mem1_out, p2buf, spk1_out, x, w1, b1);

    // 3) cur2 = spk1 @ W2^T + b2 (f64 acc -> f32) + output Leaky, fused:
    //    one block per batch row.
    gemm2_lout_fused<<<BATCH, 512, 0, stream>>>(
        spk1_out, w2, b2, cur2_out, spk2_out, mem2_out);
}